// Round 9
// baseline (85.750 us; speedup 1.0000x reference)
//
#include <hip/hip_runtime.h>

// Causal linear attention (ELU+1), chunked bf16-MFMA, 3 plain launches.
// R9: k_out re-split 8x16 rows (512 blocks x 256 thr):
//  - causal truncation: stage/compute only kceil=roundup32((rs+1)*16) rows
//    of phiK & V^T (avg 56% of staging + GEMM2/3 MFMA work)
//  - 76.5 KB LDS -> 2 blocks/CU (launch_bounds(256,2)): cross-block overlap
//  - z fully in registers: B=ones / kprev-splat z-fragments have identical
//    columns -> every lane holds z(row q*4+e) in elem e; no sZ, no final sync
// k1/k_scan unchanged from R8 (verified).
// Harness floor ~47-50us (256MB ws poison fill + input restore), not
// controllable from kernel source.

#define EPS 1e-6f

constexpr int Bc = 2;
constexpr int L  = 4096;
constexpr int D  = 128;
constexpr int C  = 128;
constexpr int NC = L / C;   // 32
constexpr int P  = 136;     // LDS row pitch (bf16), rows 16B-aligned

typedef short sh8 __attribute__((ext_vector_type(8)));
typedef float f4  __attribute__((ext_vector_type(4)));

__device__ __forceinline__ float phi(float x) {
    return x > 0.0f ? x + 1.0f : __expf(x);
}
__device__ __forceinline__ unsigned short f2bf(float f) {
    unsigned u = __float_as_uint(f);
    return (unsigned short)((u + 0x7FFFu + ((u >> 16) & 1u)) >> 16);  // RNE
}
__device__ __forceinline__ float bf2f(unsigned short h) {
    return __uint_as_float(((unsigned)h) << 16);
}
__device__ __forceinline__ unsigned packbf(float a, float b) {
    return (unsigned)f2bf(a) | ((unsigned)f2bf(b) << 16);
}
__device__ __forceinline__ sh8 splat1() {
    sh8 s;
#pragma unroll
    for (int j = 0; j < 8; ++j) s[j] = (short)0x3F80;
    return s;
}

// ---------------------------------------------------------------------------
// k1 (NC,B,2), 512 thr: S_c^T[v][i] = sum_l V[l][v] phiK[l][i] + ksum.
// Coalesced reads; transposes in LDS via swizzle. (unchanged from R8)
// ---------------------------------------------------------------------------
__global__ __launch_bounds__(512) void k1(
    const float* __restrict__ K, const float* __restrict__ V,
    unsigned short* __restrict__ SB, float* __restrict__ Ksum) {
    const int c = blockIdx.x, b = blockIdx.y, vs = blockIdx.z;
    const int tid = threadIdx.x;
    __shared__ __align__(16) unsigned short sVT[64 * P];   // V^T slice [vr][l]
    __shared__ __align__(16) unsigned short sKT[128 * P];  // phiK^T [i][l]
    const size_t base = ((size_t)b * L + (size_t)c * C) * D;

    for (int k = 0; k < 4; ++k) {
        int fi = tid + 512 * k;
        int l = fi >> 4, c4 = fi & 15;
        float4 vd = *(const float4*)(V + base + (size_t)l * D + vs * 64 + c4 * 4);
        int blk = (((l >> 3) + c4) & 15) * 8 + (l & 7);
        sVT[(c4 * 4 + 0) * P + blk] = f2bf(vd.x);
        sVT[(c4 * 4 + 1) * P + blk] = f2bf(vd.y);
        sVT[(c4 * 4 + 2) * P + blk] = f2bf(vd.z);
        sVT[(c4 * 4 + 3) * P + blk] = f2bf(vd.w);
    }
    for (int k = 0; k < 8; ++k) {
        int fi = tid + 512 * k;
        int l = fi >> 5, i4 = fi & 31;
        float4 kd = *(const float4*)(K + base + (size_t)l * D + i4 * 4);
        int blk = (((l >> 3) + i4) & 15) * 8 + (l & 7);
        sKT[(i4 * 4 + 0) * P + blk] = f2bf(phi(kd.x));
        sKT[(i4 * 4 + 1) * P + blk] = f2bf(phi(kd.y));
        sKT[(i4 * 4 + 2) * P + blk] = f2bf(phi(kd.z));
        sKT[(i4 * 4 + 3) * P + blk] = f2bf(phi(kd.w));
    }
    __syncthreads();

    const int w = tid >> 6, lane = tid & 63;
    const int r = lane & 15, q = lane >> 4;
    const int rbase = (w & 3) * 16;
    const int cbase = (w >> 2) * 64;
    const bool doK = ((w & 3) == 0);
    const sh8 ones = splat1();

    f4 acc[4], kz[4];
#pragma unroll
    for (int f = 0; f < 4; ++f) { acc[f] = {0.f,0.f,0.f,0.f}; kz[f] = {0.f,0.f,0.f,0.f}; }
#pragma unroll
    for (int ks = 0; ks < 4; ++ks) {
        int kq = ks * 4 + q;
        int vr = rbase + r;
        sh8 a = *(const sh8*)(sVT + vr * P + ((kq + (vr >> 2)) & 15) * 8);
#pragma unroll
        for (int f = 0; f < 4; ++f) {
            int ir = cbase + f * 16 + r;
            sh8 bk = *(const sh8*)(sKT + ir * P + ((kq + (ir >> 2)) & 15) * 8);
            acc[f] = __builtin_amdgcn_mfma_f32_16x16x32_bf16(a, bk, acc[f], 0, 0, 0);
            if (doK) kz[f] = __builtin_amdgcn_mfma_f32_16x16x32_bf16(ones, bk, kz[f], 0, 0, 0);
        }
    }
    unsigned short* out = SB + ((size_t)(b * NC + c)) * D * D;
#pragma unroll
    for (int f = 0; f < 4; ++f) {
        int i = cbase + f * 16 + r;
#pragma unroll
        for (int e = 0; e < 4; ++e) {
            int v = vs * 64 + rbase + q * 4 + e;
            out[(size_t)v * D + i] = f2bf(acc[f][e]);
        }
    }
    if (doK && q == 0 && vs == 0) {
#pragma unroll
        for (int f = 0; f < 4; ++f)
            Ksum[((size_t)(b * NC + c)) * D + cbase + f * 16 + r] = kz[f][0];
    }
}

// ---------------------------------------------------------------------------
// k_scan: exclusive prefix over chunks, prefetch-all-32. (unchanged from R8)
// ---------------------------------------------------------------------------
__global__ __launch_bounds__(256) void k_scan(unsigned short* __restrict__ SB,
                                              float* __restrict__ Ksum) {
    const int SD = D * D;
    int idx = blockIdx.x * 256 + threadIdx.x;
    if (idx < Bc * SD) {
        int b = idx / SD, e = idx % SD;
        size_t off0 = (size_t)b * NC * SD + e;
        unsigned short vals[NC];
#pragma unroll
        for (int c = 0; c < NC; ++c) vals[c] = SB[off0 + (size_t)c * SD];
        float run = 0.0f;
#pragma unroll
        for (int c = 0; c < NC; ++c) {
            SB[off0 + (size_t)c * SD] = f2bf(run);
            run += bf2f(vals[c]);
        }
    } else if (idx < Bc * SD + Bc * D) {
        int rr = idx - Bc * SD;
        int b = rr >> 7, i = rr & 127;
        size_t off0 = (size_t)b * NC * D + i;
        float vals[NC];
#pragma unroll
        for (int c = 0; c < NC; ++c) vals[c] = Ksum[off0 + (size_t)c * D];
        float run = 0.0f;
#pragma unroll
        for (int c = 0; c < NC; ++c) {
            Ksum[off0 + (size_t)c * D] = run;
            run += vals[c];
        }
    }
}

// ---------------------------------------------------------------------------
// k_out (NC,B,8), 16 rows/block, 256 thr (4 waves, one 32-col quarter each).
// Causal-truncated staging & GEMMs; z redundant per-wave in registers.
// LDS 76.5 KB -> 2 blocks/CU.
// ---------------------------------------------------------------------------
__global__ __launch_bounds__(256, 2) void k_out(
    const float* __restrict__ Q, const float* __restrict__ K,
    const float* __restrict__ V, const unsigned short* __restrict__ SB,
    const float* __restrict__ Ksum, float* __restrict__ Out) {
    const int c = blockIdx.x, b = blockIdx.y, rs = blockIdx.z;  // rs 0..7
    const int tid = threadIdx.x;
    __shared__ __align__(16) unsigned short sQ[16 * P];    // phiQ rows
    __shared__ __align__(16) unsigned short sK[128 * P];   // phiK rows -> S^T
    __shared__ __align__(16) unsigned short sVT[128 * P];  // V^T swizzled
    __shared__ __align__(16) unsigned short sAm[16 * P];   // masked A
    const size_t base  = ((size_t)b * L + (size_t)c * C) * D;
    const size_t tbase = ((size_t)(b * NC + c)) * (size_t)D * D;
    const size_t kb    = ((size_t)(b * NC + c)) * D;
    const int nrow  = (rs + 1) * 16;
    const int kceil = min(128, (nrow + 31) & ~31);   // staged/compute rows

    // phiQ rows rs*16..+16 (512 float4)
    for (int k = 0; k < 2; ++k) {
        int fi = tid + 256 * k;
        int row = fi >> 5, c4 = fi & 31;
        float4 qd = *(const float4*)(Q + base + (size_t)(rs * 16 + row) * D + c4 * 4);
        uint2 pq; pq.x = packbf(phi(qd.x), phi(qd.y)); pq.y = packbf(phi(qd.z), phi(qd.w));
        *(uint2*)(sQ + row * P + c4 * 4) = pq;
    }
    // phiK rows [0, kceil)  (kceil*32 float4, coalesced)
    for (int fi = tid; fi < kceil * 32; fi += 256) {
        int row = fi >> 5, c4 = fi & 31;
        float4 kd = *(const float4*)(K + base + (size_t)row * D + c4 * 4);
        uint2 pk; pk.x = packbf(phi(kd.x), phi(kd.y)); pk.y = packbf(phi(kd.z), phi(kd.w));
        *(uint2*)(sK + row * P + c4 * 4) = pk;
    }
    // V^T swizzled, l in [0, kceil)
    for (int fi = tid; fi < kceil * 32; fi += 256) {
        int l = fi >> 5, i4 = fi & 31;
        float4 vd = *(const float4*)(V + base + (size_t)l * D + i4 * 4);
        int blk = (((l >> 3) + i4) & 15) * 8 + (l & 7);
        sVT[(i4 * 4 + 0) * P + blk] = f2bf(vd.x);
        sVT[(i4 * 4 + 1) * P + blk] = f2bf(vd.y);
        sVT[(i4 * 4 + 2) * P + blk] = f2bf(vd.z);
        sVT[(i4 * 4 + 3) * P + blk] = f2bf(vd.w);
    }
    __syncthreads();                       // S1

    const int w = tid >> 6, lane = tid & 63;
    const int r = lane & 15, q = lane >> 4;
    const int cbase = w * 32;
    int flim = (kceil - cbase + 15) >> 4;  // frags with jstart < kceil
    flim = flim < 0 ? 0 : (flim > 2 ? 2 : flim);

    // kprev B-frags for GEMM4 z (r-invariant; every wave, L2-hot)
    sh8 bzk[4];
#pragma unroll
    for (int ks = 0; ks < 4; ++ks) {
        float4 f0 = *(const float4*)(Ksum + kb + ks * 32 + q * 8);
        float4 f1 = *(const float4*)(Ksum + kb + ks * 32 + q * 8 + 4);
        sh8 t;
        t[0] = (short)f2bf(f0.x); t[1] = (short)f2bf(f0.y);
        t[2] = (short)f2bf(f0.z); t[3] = (short)f2bf(f0.w);
        t[4] = (short)f2bf(f1.x); t[5] = (short)f2bf(f1.y);
        t[6] = (short)f2bf(f1.z); t[7] = (short)f2bf(f1.w);
        bzk[ks] = t;
    }

    // ---- GEMM2: A = phiQ phiK^T (cols truncated to kceil) ----
    f4 a2[2];
    a2[0] = {0.f,0.f,0.f,0.f}; a2[1] = {0.f,0.f,0.f,0.f};
#pragma unroll
    for (int ks = 0; ks < 4; ++ks) {
        sh8 a = *(const sh8*)(sQ + r * P + ks * 32 + q * 8);
        for (int f = 0; f < flim; ++f) {
            sh8 bb = *(const sh8*)(sK + (cbase + f * 16 + r) * P + ks * 32 + q * 8);
            a2[f] = __builtin_amdgcn_mfma_f32_16x16x32_bf16(a, bb, a2[f], 0, 0, 0);
        }
    }
    for (int f = 0; f < flim; ++f) {       // causal mask -> sAm bf16
        int j = cbase + f * 16 + r;
#pragma unroll
        for (int e = 0; e < 4; ++e) {
            int lr = q * 4 + e;
            sAm[lr * P + j] = f2bf((j <= rs * 16 + lr) ? a2[f][e] : 0.f);
        }
    }
    __syncthreads();                       // S2: sAm ready, sK reads done

    // restage sK <- S_prev^T (2048 uint4; overlaps GEMM3 issue)
    {
        const uint4* sg = (const uint4*)(SB + tbase);
        for (int k = 0; k < 8; ++k) {
            int f2 = tid + 256 * k;
            *(uint4*)(sK + (f2 >> 4) * P + (f2 & 15) * 8) = sg[f2];
        }
    }

    // ---- GEMM3: acc = Am @ V, k-loop truncated; + rowsum z (ones-B) ----
    f4 acc[2], zacc = {0.f,0.f,0.f,0.f};
    acc[0] = {0.f,0.f,0.f,0.f}; acc[1] = {0.f,0.f,0.f,0.f};
    const sh8 ones = splat1();
    const int ks3 = kceil >> 5;
    for (int ks = 0; ks < ks3; ++ks) {
        int kq = ks * 4 + q;
        sh8 am = *(const sh8*)(sAm + r * P + ks * 32 + q * 8);
#pragma unroll
        for (int f = 0; f < 2; ++f) {
            int vr = cbase + f * 16 + r;
            sh8 bv = *(const sh8*)(sVT + vr * P + ((kq + (vr >> 2)) & 15) * 8);
            acc[f] = __builtin_amdgcn_mfma_f32_16x16x32_bf16(am, bv, acc[f], 0, 0, 0);
        }
        zacc = __builtin_amdgcn_mfma_f32_16x16x32_bf16(am, ones, zacc, 0, 0, 0);
    }
    __syncthreads();                       // S3: sK = S^T ready

    // ---- GEMM4: acc += phiQ @ S_prev; + kprev z ----
#pragma unroll
    for (int ks = 0; ks < 4; ++ks) {
        sh8 a = *(const sh8*)(sQ + r * P + ks * 32 + q * 8);
#pragma unroll
        for (int f = 0; f < 2; ++f) {
            sh8 bs = *(const sh8*)(sK + (cbase + f * 16 + r) * P + ks * 32 + q * 8);
            acc[f] = __builtin_amdgcn_mfma_f32_16x16x32_bf16(a, bs, acc[f], 0, 0, 0);
        }
        zacc = __builtin_amdgcn_mfma_f32_16x16x32_bf16(a, bzk[ks], zacc, 0, 0, 0);
    }

    // ---- normalize + store: z-frag cols identical -> zacc[e] = z(row q*4+e)
    // in EVERY lane; same e-indexing as acc. No LDS, no sync. ----
#pragma unroll
    for (int e = 0; e < 4; ++e) {
        int lr = q * 4 + e;
        float rz = 1.0f / (zacc[e] + EPS);
#pragma unroll
        for (int f = 0; f < 2; ++f) {
            int v = cbase + f * 16 + r;
            Out[base + (size_t)(rs * 16 + lr) * D + v] = acc[f][e] * rz;
        }
    }
}

extern "C" void kernel_launch(void* const* d_in, const int* in_sizes, int n_in,
                              void* d_out, int out_size, void* d_ws, size_t ws_size,
                              hipStream_t stream) {
    const float* Q = (const float*)d_in[0];
    const float* K = (const float*)d_in[1];
    const float* V = (const float*)d_in[2];
    float* Out = (float*)d_out;
    unsigned short* SBw = (unsigned short*)d_ws;                        // 2 MB
    float* Ksum = (float*)((char*)d_ws + (size_t)Bc * NC * D * D * 2);  // 32 KB

    k1<<<dim3(NC, Bc, 2), 512, 0, stream>>>(K, V, SBw, Ksum);
    int total = Bc * D * D + Bc * D;
    k_scan<<<dim3((total + 255) / 256), 256, 0, stream>>>(SBw, Ksum);
    k_out<<<dim3(NC, Bc, 8), 256, 0, stream>>>(Q, K, V, SBw, Ksum, Out);
}